// Round 1
// baseline (256.976 us; speedup 1.0000x reference)
//
#include <hip/hip_runtime.h>

#define NZ 1e-5f
#define TC 16   // timesteps per staged LDS tile

__device__ __forceinline__ float fast_exp2(float x) {
#if __has_builtin(__builtin_amdgcn_exp2f)
    return __builtin_amdgcn_exp2f(x);   // v_exp_f32
#else
    return exp2f(x);
#endif
}

__device__ __forceinline__ float fast_log2(float x) {
#if __has_builtin(__builtin_amdgcn_logf)
    return __builtin_amdgcn_logf(x);    // v_log_f32 (base-2)
#else
    return log2f(x);
#endif
}

// Async global->LDS, 16B/lane. LDS dest is wave-uniform base + lane*16;
// global source address is per-lane (this is how we get the [t][g] tile layout).
__device__ __forceinline__ void gload_lds16(const float* src, float* dst_lds) {
    __builtin_amdgcn_global_load_lds(
        (const __attribute__((address_space(1))) void*)src,
        (__attribute__((address_space(3))) void*)dst_lds,
        16, 0, 0);
}

// Only 782 waves exist in the whole problem (<1 wave/SIMD): occupancy cannot be
// raised, so ALL latency hiding must be ILP/async. (64,1) keeps the full VGPR
// budget available. The register prefetch ring of the previous version was
// collapsed by the register allocator (VGPR_Count=36 < ring working set) --
// this version stages forcings through LDS via global_load_lds instead, which
// the compiler cannot de-pipeline.
__global__ __launch_bounds__(64, 1) void hbv_kernel(
    const float* __restrict__ precip,
    const float* __restrict__ temp,
    const float* __restrict__ pet,
    const float* __restrict__ phy,
    float* __restrict__ out,
    int G, int T)
{
    // [buf][array][t_sub][g_sub] : 2*3*16*64*4 = 24576 B
    __shared__ float lds[2][3][TC][64];

    const int lane = threadIdx.x;            // 0..63
    const int g0   = blockIdx.x * 64;
    const int g    = g0 + lane;
    const bool valid = (g < G);
    const int gp   = valid ? g : (G - 1);    // clamped for param load (no early
                                             // return: all lanes must stage)

    // Parameter bounds (compile-time constants, folded)
    const float lo[14] = {1.0f, 50.0f, 0.05f, 0.01f, 0.001f, 0.2f, 0.0f,
                          0.0f, -2.5f, 0.5f, 0.0f, 0.0f, 0.3f, 0.0f};
    const float hi[14] = {6.0f, 1000.0f, 0.9f, 0.5f, 0.2f, 1.0f, 10.0f,
                          100.0f, 2.5f, 10.0f, 0.1f, 0.2f, 5.0f, 1.0f};
    float p[14];
#pragma unroll
    for (int i = 0; i < 14; ++i)
        p[i] = lo[i] + phy[gp * 14 + i] * (hi[i] - lo[i]);

    const float BETA = p[0], FC = p[1], K0 = p[2], K1 = p[3], K2 = p[4];
    const float LP = p[5], PERCp = p[6], UZL = p[7], TT = p[8], CFMAX = p[9];
    const float CFR = p[10], CWH = p[11], BETAET = p[12], C = p[13];
    const float invFC   = 1.0f / FC;
    const float invLPFC = 1.0f / (LP * FC);
    const float CFRX    = CFR * CFMAX;

    // State (registers for the whole scan)
    float SP = NZ, MW = NZ, SM = NZ, SUZ = NZ, SLZ = NZ;

    // --- HBV step: byte-identical math to the verified passing kernel ---
    auto hbv_step = [&](float pr, float tm, float pe) -> float {
        const float RAIN = (tm >= TT) ? pr : 0.0f;
        const float SNOW = pr - RAIN;
        SP += SNOW;
        float melt = fminf(fmaxf(CFMAX * (tm - TT), 0.0f), SP);
        MW += melt;
        SP -= melt;
        float refr = fminf(fmaxf(CFRX * (TT - tm), 0.0f), MW);
        SP += refr;
        MW -= refr;
        float tosoil = fmaxf(MW - CWH * SP, 0.0f);
        MW -= tosoil;
        float sw = fminf(fast_exp2(BETA * fast_log2(SM * invFC)), 1.0f);
        float rt = RAIN + tosoil;
        float recharge = rt * sw;
        SM += rt - recharge;
        float excess = fmaxf(SM - FC, 0.0f);
        SM -= excess;
        float ef = fminf(fast_exp2(BETAET * fast_log2(SM * invLPFC)), 1.0f);
        float ETact = fminf(SM, pe * ef);
        SM = fmaxf(SM - ETact, NZ);
        float cap = fminf(SLZ, C * SLZ * (1.0f - fminf(SM * invFC, 1.0f)));
        SM = fmaxf(SM + cap, NZ);
        SLZ = fmaxf(SLZ - cap, NZ);
        SUZ += recharge + excess;
        float PERC = fminf(SUZ, PERCp);
        SUZ -= PERC;
        float Q0 = K0 * fmaxf(SUZ - UZL, 0.0f);
        SUZ -= Q0;
        float Q1 = K1 * SUZ;
        SUZ -= Q1;
        SLZ = fmaxf(SLZ + PERC, 0.0f);
        float Q2 = K2 * SLZ;
        SLZ -= Q2;
        return Q0 + Q1 + Q2;
    };

    if ((G & 3) == 0) {
        // ---- fast path: async LDS staging (needs 16B-aligned rows: G%4==0) ----
        const int rsub = lane >> 4;          // which row of the 4-row quad
        const int csub = (lane & 15) << 2;   // float col within the 64-basin row
        int gcol = g0 + csub;
        if (gcol > G - 4) gcol = G - 4;      // clamp (only ever hits invalid basins)

        const int nt = (T + TC - 1) / TC;

        // One tile = 16 rows x 64 basins x 3 arrays. Each width-16 load covers
        // 4 rows (64 lanes x 16B = 1KiB): 4 instrs/array, 12 per tile.
        auto issue_tile = [&](int k, int b) {
            const int t0 = k * TC;
#pragma unroll
            for (int q = 0; q < TC / 4; ++q) {
                int t = t0 + 4 * q + rsub;
                if (t > T - 1) t = T - 1;    // tail clamp: duplicate rows, never consumed
                const size_t off = (size_t)t * G + gcol;
                gload_lds16(precip + off, &lds[b][0][4 * q][0]);
                gload_lds16(temp   + off, &lds[b][1][4 * q][0]);
                gload_lds16(pet    + off, &lds[b][2][4 * q][0]);
            }
        };

        issue_tile(0, 0);
        asm volatile("s_waitcnt vmcnt(0)" ::: "memory");
        __builtin_amdgcn_sched_barrier(0);

        for (int k = 0; k < nt; ++k) {
            const int b = k & 1;
            if (k + 1 < nt) {
                issue_tile(k + 1, b ^ 1);            // 12 loads in flight across the
                __builtin_amdgcn_sched_barrier(0);   // whole compute phase below
            }
            const int t0 = k * TC;
#pragma unroll
            for (int j = 0; j < TC; ++j) {
                const int t = t0 + j;
                const float pr = lds[b][0][j][lane]; // stride-1: 2-way bank alias, free
                const float tm = lds[b][1][j][lane];
                const float pe = lds[b][2][j][lane];
                const float q = hbv_step(pr, tm, pe);
                if (valid && t < T)
                    out[(size_t)t * G + g] = q;
            }
            if (k + 1 < nt) {
                // Counted wait (T4): the 12 newest-but-some vmem ops are this tile's
                // 16 stores; allowing 12 outstanding retires the next tile's 12 loads
                // (issued ~4000 cycles ago -> zero stall) without draining stores.
                asm volatile("s_waitcnt vmcnt(12)" ::: "memory");
                __builtin_amdgcn_sched_barrier(0);
            }
        }
    } else {
        // ---- generic fallback (not taken for the bench shape) ----
        for (int t = 0; t < T; ++t) {
            const size_t idx = (size_t)t * G + gp;
            const float q = hbv_step(precip[idx], temp[idx], pet[idx]);
            if (valid) out[idx] = q;
        }
    }
}

extern "C" void kernel_launch(void* const* d_in, const int* in_sizes, int n_in,
                              void* d_out, int out_size, void* d_ws, size_t ws_size,
                              hipStream_t stream) {
    const float* precip = (const float*)d_in[0];
    const float* temp   = (const float*)d_in[1];
    const float* pet    = (const float*)d_in[2];
    const float* phy    = (const float*)d_in[3];
    float* out = (float*)d_out;

    const int G = in_sizes[3] / 14;   // 50000
    const int T = in_sizes[0] / G;    // 365

    dim3 block(64);
    dim3 grid((G + 63) / 64);         // 782 blocks -> all 256 CUs covered
    hbv_kernel<<<grid, block, 0, stream>>>(precip, temp, pet, phy, out, G, T);
}